// Round 17
// baseline (120.121 us; speedup 1.0000x reference)
//
#include <hip/hip_runtime.h>

// ---------------------------------------------------------------------------
// Compile-time wavelet-packet response matrix A[64][50].
// ---------------------------------------------------------------------------
struct Amat { float a[64][50]; };

constexpr Amat makeA() {
    constexpr float h0[4] = { 0.48296291314453416f,  0.8365163037378079f,
                              0.22414386804185735f, -0.12940952255126037f};
    constexpr float h1[4] = {-0.48296291314453416f, 0.8365163037378079f,
                             -0.22414386804185735f, -0.12940952255126037f};
    // NOTE: filters below are the pre-reversed taps actually used everywhere
    // (kept identical to the R16-verified constants).
    constexpr float g0[4] = { 0.48296291314453416f,  0.8365163037378079f,
                              0.22414386804185735f, -0.12940952255126037f};
    constexpr float g1[4] = {-0.12940952255126037f, -0.22414386804185735f,
                              0.8365163037378079f,  -0.48296291314453416f};
    (void)h0; (void)h1;
    float L1[2][26][50] = {};
    for (int band = 0; band < 2; ++band)
        for (int m = 0; m < 26; ++m)
            for (int n = 0; n < 50; ++n) {
                int k = n - 2 * m + 2;
                L1[band][m][n] = (k >= 0 && k < 4) ? (band ? g1[k] : g0[k]) : 0.0f;
            }
    float L2[4][14][50] = {};
    for (int j = 0; j < 4; ++j)
        for (int m = 0; m < 14; ++m)
            for (int n = 0; n < 50; ++n) {
                float acc = 0.0f;
                for (int k = 0; k < 4; ++k) {
                    int p = 2 * m + k - 2;
                    if (p >= 0 && p < 26)
                        acc += (j & 1 ? g1[k] : g0[k]) * L1[j >> 1][p][n];
                }
                L2[j][m][n] = acc;
            }
    Amat A = {};
    for (int j = 0; j < 8; ++j)
        for (int m = 0; m < 8; ++m)
            for (int n = 0; n < 50; ++n) {
                float acc = 0.0f;
                for (int k = 0; k < 4; ++k) {
                    int p = 2 * m + k - 2;
                    if (p >= 0 && p < 14)
                        acc += (j & 1 ? g1[k] : g0[k]) * L2[j >> 1][p][n];
                }
                A.a[j * 8 + m][n] = acc;
            }
    return A;
}

__device__ __constant__ Amat cA = makeA();

#define MAGIC0 0x5A17EC0D
#define MAGIC1 0x0DEC175A

// DPP-add: v += dpp_perm(v). CTRL: 0xB1 = quad_perm xor1, 0x4E = quad_perm
// xor2, 0x141 = row_half_mirror (maps each 8-lane half onto itself, swapping
// quads -> completes the 8-lane reduction). All VALU pipe, zero LDS.
template <int CTRL>
__device__ __forceinline__ float dpp_add(float v) {
    const int r = __builtin_amdgcn_update_dpp(
        __float_as_int(v), __float_as_int(v), CTRL, 0xF, 0xF, false);
    return v + __int_as_float(r);
}

// ---------------------------------------------------------------------------
// Single fused kernel. 1024 blocks x 256 threads, __launch_bounds__(256,4)
// + 9.6 KB LDS -> all 1024 blocks co-resident (4/CU, 16 waves/CU).
//
// Block 0: folds W+bias with cA into step-major M (fi = i>>1, p = i&1:
// slot fi*10 + k*2 + p; fi 75..79 zero; bias at 800+k), writes it to BOTH
// its own sM and d_ws, then release-publishes a 2-word flag. Other blocks
// acquire-spin (tid 0 only) then load sM from d_ws. d_ws is poisoned once
// before timing -> every timed replay after the first is spin-free.
//
// gemv: 8 lanes per row, 4 rows per thread (g, g+32, g+64, g+96 of the
// block's 128). Step s: 8 lanes read 8 consecutive float2 = 64 B contiguous
// per row (consume-once). All 40 x-loads = 4 base addrs + static offsets.
// M: 50 ds_read_b64 (lg-stride 10 dwords -> distinct banks, broadcast).
// Reduce: 3 DPP adds (xor1, xor2, half-mirror). Funnel store via sO.
// ---------------------------------------------------------------------------
__global__ __launch_bounds__(256, 4) void dwt_all(const float* __restrict__ x,
                                                  const float* __restrict__ W,
                                                  const float* __restrict__ bias,
                                                  float* __restrict__ out,
                                                  float* __restrict__ ws) {
    __shared__ float sM[805];
    __shared__ float sO[128 * 5];
    __shared__ float sW[960];
    const int tid = threadIdx.x;
    int* flag = (int*)(ws + 1024);

    if (blockIdx.x == 0) {
        // ---- fold (R16-verified math), write sM + d_ws, publish ----
        #pragma unroll
        for (int t = 0; t < 4; ++t) {
            const int idx = tid + t * 256;
            if (idx < 960) sW[idx] = W[idx];
        }
        __syncthreads();
        if (tid < 150) {
            const int c = tid / 50, n = tid - c * 50;
            float m0 = 0.f, m1 = 0.f, m2 = 0.f, m3 = 0.f, m4 = 0.f;
            #pragma unroll 16
            for (int f = 0; f < 64; ++f) {          // f = j*8 + s
                const float av = cA.a[f][n];
                const int wj = (f >> 3) * 24 + c * 8 + (f & 7);
                m0 = fmaf(sW[0 * 192 + wj], av, m0);
                m1 = fmaf(sW[1 * 192 + wj], av, m1);
                m2 = fmaf(sW[2 * 192 + wj], av, m2);
                m3 = fmaf(sW[3 * 192 + wj], av, m3);
                m4 = fmaf(sW[4 * 192 + wj], av, m4);
            }
            const int base = (tid >> 1) * 10 + (tid & 1);
            sM[base + 0] = m0;  ws[base + 0] = m0;
            sM[base + 2] = m1;  ws[base + 2] = m1;
            sM[base + 4] = m2;  ws[base + 4] = m2;
            sM[base + 6] = m3;  ws[base + 6] = m3;
            sM[base + 8] = m4;  ws[base + 8] = m4;
        } else if (tid < 160) {                      // fi 75..79 -> zeros
            const int base = (tid >> 1) * 10 + (tid & 1);
            #pragma unroll
            for (int k = 0; k < 5; ++k) { sM[base + 2 * k] = 0.f; ws[base + 2 * k] = 0.f; }
        } else if (tid < 165) {
            const float b = bias[tid - 160];
            sM[800 + (tid - 160)] = b;  ws[800 + (tid - 160)] = b;
        }
        __syncthreads();
        if (tid == 0) {
            __hip_atomic_store(flag + 0, MAGIC0, __ATOMIC_RELEASE, __HIP_MEMORY_SCOPE_AGENT);
            __hip_atomic_store(flag + 1, MAGIC1, __ATOMIC_RELEASE, __HIP_MEMORY_SCOPE_AGENT);
        }
    } else {
        if (tid == 0) {
            while (__hip_atomic_load(flag + 0, __ATOMIC_ACQUIRE, __HIP_MEMORY_SCOPE_AGENT) != MAGIC0 ||
                   __hip_atomic_load(flag + 1, __ATOMIC_ACQUIRE, __HIP_MEMORY_SCOPE_AGENT) != MAGIC1)
                __builtin_amdgcn_s_sleep(8);
        }
        __syncthreads();
        #pragma unroll
        for (int t = 0; t < 4; ++t) {
            const int idx = tid + t * 256;
            if (idx < 805) sM[idx] = ws[idx];
        }
        __syncthreads();
    }

    // ---- gemv ----
    const int g  = tid >> 3;                 // row group 0..31
    const int lg = tid & 7;                  // lane in octet
    const size_t r0 = (size_t)blockIdx.x * 128 + g;
    const float2* __restrict__ x2 = (const float2*)x;   // row r at r*75

    float acc[4][5] = {{0,0,0,0,0},{0,0,0,0,0},{0,0,0,0,0},{0,0,0,0,0}};

    #pragma unroll
    for (int s = 0; s < 10; ++s) {
        const int fi = s * 8 + lg;                       // logical float2 idx
        const int fx = (s == 9) ? ((fi < 75) ? fi : 74) : fi;   // clamp tail
        const float2 v0 = x2[(r0     ) * 75 + fx];
        const float2 v1 = x2[(r0 + 32) * 75 + fx];
        const float2 v2 = x2[(r0 + 64) * 75 + fx];
        const float2 v3 = x2[(r0 + 96) * 75 + fx];
        #pragma unroll
        for (int k = 0; k < 5; ++k) {
            const float2 m = *(const float2*)&sM[fi * 10 + k * 2];  // 0 for fi>=75
            acc[0][k] = fmaf(m.y, v0.y, fmaf(m.x, v0.x, acc[0][k]));
            acc[1][k] = fmaf(m.y, v1.y, fmaf(m.x, v1.x, acc[1][k]));
            acc[2][k] = fmaf(m.y, v2.y, fmaf(m.x, v2.x, acc[2][k]));
            acc[3][k] = fmaf(m.y, v3.y, fmaf(m.x, v3.x, acc[3][k]));
        }
    }

    // 8-lane reduce: xor1, xor2 (quad_perm), then half-mirror (quad swap)
    #pragma unroll
    for (int r = 0; r < 4; ++r)
        #pragma unroll
        for (int k = 0; k < 5; ++k)
            acc[r][k] = dpp_add<0x141>(dpp_add<0x4E>(dpp_add<0xB1>(acc[r][k])));

    if (lg == 0) {
        #pragma unroll
        for (int r = 0; r < 4; ++r)
            #pragma unroll
            for (int k = 0; k < 5; ++k)
                sO[(g + 32 * r) * 5 + k] = acc[r][k] + sM[800 + k];
    }
    __syncthreads();

    for (int idx = tid; idx < 640; idx += 256)
        out[(size_t)blockIdx.x * 640 + idx] = sO[idx];
}

extern "C" void kernel_launch(void* const* d_in, const int* in_sizes, int n_in,
                              void* d_out, int out_size, void* d_ws, size_t ws_size,
                              hipStream_t stream) {
    const float* x    = (const float*)d_in[0];   // (131072, 3, 50)
    const float* W    = (const float*)d_in[1];   // (5, 192)
    const float* bias = (const float*)d_in[2];   // (5,)
    float*       out  = (float*)d_out;           // (131072, 5)
    float*       ws   = (float*)d_ws;            // [0..804] M, [1024..1025] flag

    const int B    = in_sizes[0] / 150;          // 131072 rows
    const int grid = B / 128;                    // 1024 blocks (4/CU, all resident)
    dwt_all<<<grid, 256, 0, stream>>>(x, W, bias, out, ws);
}

// Round 18
// 25.917 us; speedup vs baseline: 4.6349x; 4.6349x over previous
//
#include <hip/hip_runtime.h>

// ---------------------------------------------------------------------------
// Compile-time wavelet-packet response matrix A[64][50].
// ---------------------------------------------------------------------------
struct Amat { float a[64][50]; };

constexpr Amat makeA() {
    constexpr float h0[4] = { 0.48296291314453416f,  0.8365163037378079f,
                              0.22414386804185735f, -0.12940952255126037f};
    constexpr float h1[4] = {-0.12940952255126037f, -0.22414386804185735f,
                              0.8365163037378079f,  -0.48296291314453416f};
    float L1[2][26][50] = {};
    for (int band = 0; band < 2; ++band)
        for (int m = 0; m < 26; ++m)
            for (int n = 0; n < 50; ++n) {
                int k = n - 2 * m + 2;
                L1[band][m][n] = (k >= 0 && k < 4) ? (band ? h1[k] : h0[k]) : 0.0f;
            }
    float L2[4][14][50] = {};
    for (int j = 0; j < 4; ++j)
        for (int m = 0; m < 14; ++m)
            for (int n = 0; n < 50; ++n) {
                float acc = 0.0f;
                for (int k = 0; k < 4; ++k) {
                    int p = 2 * m + k - 2;
                    if (p >= 0 && p < 26)
                        acc += (j & 1 ? h1[k] : h0[k]) * L1[j >> 1][p][n];
                }
                L2[j][m][n] = acc;
            }
    Amat A = {};
    for (int j = 0; j < 8; ++j)
        for (int m = 0; m < 8; ++m)
            for (int n = 0; n < 50; ++n) {
                float acc = 0.0f;
                for (int k = 0; k < 4; ++k) {
                    int p = 2 * m + k - 2;
                    if (p >= 0 && p < 14)
                        acc += (j & 1 ? h1[k] : h0[k]) * L2[j >> 1][p][n];
                }
                A.a[j * 8 + m][n] = acc;
            }
    return A;
}

__device__ __constant__ Amat cA = makeA();

// ---------------------------------------------------------------------------
// Kernel 1 (1 block): fold W+bias into PACKED step-major layout, stride 12:
//   feature i -> fi = i>>1, p = i&1;  Mp[fi*12 + k*2 + p] = M[i][k]
//   Mp[fi*12 + 10/11] = 0 (pad),  Mp[900+k] = bias[k].   (905 floats)
// Stride 12 (48 B) => fi*12 is 16B-aligned: QSTEP reads 2 b128 + 1 b64.
// ---------------------------------------------------------------------------
__global__ __launch_bounds__(256) void build_M(const float* __restrict__ W,
                                               const float* __restrict__ bias,
                                               float* __restrict__ Mp) {
    __shared__ float sW[960];
    const int tid = threadIdx.x;
    #pragma unroll
    for (int t = 0; t < 4; ++t) {
        const int idx = tid + t * 256;
        if (idx < 960) sW[idx] = W[idx];
    }
    __syncthreads();

    if (tid < 150) {
        const int c = tid / 50, n = tid - c * 50;
        float m0 = 0.f, m1 = 0.f, m2 = 0.f, m3 = 0.f, m4 = 0.f;
        #pragma unroll 16
        for (int f = 0; f < 64; ++f) {              // f = j*8 + s
            const float av = cA.a[f][n];
            const int wj = (f >> 3) * 24 + c * 8 + (f & 7);
            m0 = fmaf(sW[0 * 192 + wj], av, m0);
            m1 = fmaf(sW[1 * 192 + wj], av, m1);
            m2 = fmaf(sW[2 * 192 + wj], av, m2);
            m3 = fmaf(sW[3 * 192 + wj], av, m3);
            m4 = fmaf(sW[4 * 192 + wj], av, m4);
        }
        const int base = (tid >> 1) * 12 + (tid & 1);
        Mp[base + 0] = m0;
        Mp[base + 2] = m1;
        Mp[base + 4] = m2;
        Mp[base + 6] = m3;
        Mp[base + 8] = m4;
    } else if (tid < 225) {                          // pad slots fi*12+10/11
        const int fi = tid - 150;                    // 0..74
        Mp[fi * 12 + 10] = 0.f;
        Mp[fi * 12 + 11] = 0.f;
    } else if (tid < 230) {
        Mp[900 + (tid - 225)] = bias[tid - 225];
    }
}

// ---------------------------------------------------------------------------
// DPP quad_perm add (VALU pipe): 0xB1 = xor1 [1,0,3,2], 0x4E = xor2 [2,3,0,1].
// Proven encodings (R16 passed with them).
// ---------------------------------------------------------------------------
template <int CTRL>
__device__ __forceinline__ float dpp_add(float v) {
    const int r = __builtin_amdgcn_update_dpp(
        __float_as_int(v), __float_as_int(v), CTRL, 0xF, 0xF, false);
    return v + __int_as_float(r);
}

// ---------------------------------------------------------------------------
// Kernel 2 = R10's proven gemv (25.2us) with two issue cuts:
//  - M reads: 2 x ds_read_b128 + 1 x ds_read_b64 per step (was 5 x b64):
//    95 -> 57 LDS instr/wave. Addrs 48B apart -> distinct banks, broadcast.
//  - quad reduce via DPP quad_perm (VALU) instead of shfl_xor (LDS bpermute).
// Everything else identical: 2048 blocks x 256, 4 threads/row interleaved
// float2 (quad = 32B contiguous), lane q==0 stores.
// ---------------------------------------------------------------------------
#define QSTEP(fi)                                                        \
    {   const float2 xv = xr[(fi)];                                      \
        const float4 mA = *(const float4*)&sMt[(fi) * 12 + 0];           \
        const float4 mB = *(const float4*)&sMt[(fi) * 12 + 4];           \
        const float2 mC = *(const float2*)&sMt[(fi) * 12 + 8];           \
        a0 = fmaf(mA.x, xv.x, a0); a0 = fmaf(mA.y, xv.y, a0);            \
        a1 = fmaf(mA.z, xv.x, a1); a1 = fmaf(mA.w, xv.y, a1);            \
        a2 = fmaf(mB.x, xv.x, a2); a2 = fmaf(mB.y, xv.y, a2);            \
        a3 = fmaf(mB.z, xv.x, a3); a3 = fmaf(mB.w, xv.y, a3);            \
        a4 = fmaf(mC.x, xv.x, a4); a4 = fmaf(mC.y, xv.y, a4);            \
    }

__global__ __launch_bounds__(256, 4) void dwt_gemv(const float* __restrict__ x,
                                                   const float* __restrict__ Mp,
                                                   float* __restrict__ out) {
    __shared__ float sMt[908];
    const int tid = threadIdx.x;
    #pragma unroll
    for (int t = 0; t < 4; ++t) {
        const int idx = tid + t * 256;
        if (idx < 905) sMt[idx] = Mp[idx];
    }
    __syncthreads();

    const size_t g   = (size_t)blockIdx.x * 256 + tid;
    const size_t row = g >> 2;
    const int    q   = (int)(g & 3);
    const float2* __restrict__ xr = (const float2*)(x + row * 150);  // 8B-aligned

    float a0 = 0.f, a1 = 0.f, a2 = 0.f, a3 = 0.f, a4 = 0.f;

    // fi = 4j+q for j=0..17 (all quads), plus 72+q for q<3 -> covers 0..74
    #pragma unroll
    for (int j = 0; j < 18; ++j)
        QSTEP(4 * j + q)
    if (q < 3)
        QSTEP(72 + q)

    // quad reduction on the VALU pipe (DPP quad_perm xor1, xor2)
    a0 = dpp_add<0x4E>(dpp_add<0xB1>(a0));
    a1 = dpp_add<0x4E>(dpp_add<0xB1>(a1));
    a2 = dpp_add<0x4E>(dpp_add<0xB1>(a2));
    a3 = dpp_add<0x4E>(dpp_add<0xB1>(a3));
    a4 = dpp_add<0x4E>(dpp_add<0xB1>(a4));

    if (q == 0) {
        float* o = out + row * 5;
        o[0] = a0 + sMt[900];
        o[1] = a1 + sMt[901];
        o[2] = a2 + sMt[902];
        o[3] = a3 + sMt[903];
        o[4] = a4 + sMt[904];
    }
}

extern "C" void kernel_launch(void* const* d_in, const int* in_sizes, int n_in,
                              void* d_out, int out_size, void* d_ws, size_t ws_size,
                              hipStream_t stream) {
    const float* x    = (const float*)d_in[0];   // (131072, 3, 50)
    const float* W    = (const float*)d_in[1];   // (5, 192)
    const float* bias = (const float*)d_in[2];   // (5,)
    float*       out  = (float*)d_out;           // (131072, 5)
    float*       Mp   = (float*)d_ws;            // 905 floats

    build_M<<<1, 256, 0, stream>>>(W, bias, Mp);

    const int B    = in_sizes[0] / 150;          // 131072 rows
    const int grid = (B * 4) / 256;              // 2048 blocks, 8/CU
    dwt_gemv<<<grid, 256, 0, stream>>>(x, Mp, out);
}